// Round 5
// baseline (86.459 us; speedup 1.0000x reference)
//
#include <hip/hip_runtime.h>

// WindowEmbedding: x[B,T,D] fp32 -> out[B,T,D*W], slot w = x shifted left by w,
// zero past sequence end. B=16, T=2048, D=512, W=5.
//
// out[(b,t)] row (640 f4) = contiguous x slice starting at (b,t), zero-guarded
// at the sequence end. Rolling-register window: 1 load + 5 stores per output
// row. R=32 rows/block -> read amp 36/32 = 1.125. A/B vs R4: NORMAL stores
// (no nontemporal) — testing whether the NT path throttles the write stream
// below L2-writeback pacing (fill kernel does 7.0 TB/s with normal stores).

typedef float f4 __attribute__((ext_vector_type(4)));

constexpr int T_DIM = 2048;
constexpr int D4 = 128;            // 512 floats / 4 per float4
constexpr int W = 5;
constexpr int R = 32;              // rows per block (two 128-thread halves x 16)
constexpr int HR = R / 2;          // rows per half
constexpr int ROW_OUT = W * D4;    // 640 f4 per output row

__global__ __launch_bounds__(256) void window_embed_kernel(
    const f4* __restrict__ x, f4* __restrict__ out) {
  const int tid  = threadIdx.x;
  const int lane = tid & 127;      // f4 index within a D-row
  const int half = tid >> 7;       // which 16-row sub-chunk

  const int tbase = blockIdx.x * R + half * HR;          // first t of my chunk
  const long long row0 = (long long)blockIdx.y * T_DIM + tbase;

  const f4* __restrict__ xb = x + row0 * D4 + lane;
  f4* __restrict__ ob = out + row0 * (long long)ROW_OUT + lane;

  const f4 zero = (f4)0.f;

  // Prime the 5-row rolling window: win[q] holds x row (tbase+q) at my lane.
  f4 win[W];
#pragma unroll
  for (int q = 0; q < W; ++q)
    win[q] = (tbase + q < T_DIM) ? xb[q * D4] : zero;

  // Invariant before iter i: win[(i+w)%5] == x row (tbase+i+w), w=0..4.
#pragma unroll
  for (int i = 0; i < HR; ++i) {
#pragma unroll
    for (int w = 0; w < W; ++w) {
      ob[(long long)i * ROW_OUT + w * D4] = win[(i + w) % W];
    }
    // Refill slot i%5 with row tbase+i+5 (consumed 5 iterations later).
    win[i % W] = (tbase + i + W < T_DIM) ? xb[(i + W) * D4] : zero;
  }
}

extern "C" void kernel_launch(void* const* d_in, const int* in_sizes, int n_in,
                              void* d_out, int out_size, void* d_ws, size_t ws_size,
                              hipStream_t stream) {
  const f4* x = (const f4*)d_in[0];
  f4* out = (f4*)d_out;

  dim3 grid(T_DIM / R, 16);   // (64, 16) = 1024 blocks
  window_embed_kernel<<<grid, 256, 0, stream>>>(x, out);
}

// Round 7
// 85.599 us; speedup vs baseline: 1.0100x; 1.0100x over previous
//
#include <hip/hip_runtime.h>

// WindowEmbedding: x[B,T,D] fp32 -> out[B,T,D*W], slot w = x shifted left by w,
// zero past sequence end. B=16, T=2048, D=512, W=5.
//
// out[(b,t)] row (640 f4) = contiguous 640-f4 slice of x starting at (b,t),
// zero-guarded at the sequence end. Rolling-register window (1 nt-load +
// 5 nt-stores per output row). R=64 rows/block -> HBM read amp 68/64=1.0625.
//
// Lessons locked in:
//  - __builtin_nontemporal_store (nt-only) is required: plain stores
//    write-allocate-thrash L2/L3 (+23% time, R5); sc0/sc1 full bypass is
//    INCORRECT here (stale zero lines from the harness memset stay in cache
//    and validation reads them, R6).
//  - nt loads are safe: each x row is read exactly once per block (reuse is
//    in registers), so no cache allocation is needed on the read side.

typedef float f4 __attribute__((ext_vector_type(4)));

constexpr int T_DIM = 2048;
constexpr int D4 = 128;            // 512 floats / 4 per float4
constexpr int W = 5;
constexpr int R = 64;              // rows per block
constexpr int GROUPS = 4;          // 512 threads = 4 x 128-lane row groups
constexpr int GR = R / GROUPS;     // 16 rows per group
constexpr int ROW_OUT = W * D4;    // 640 f4 per output row

__global__ __launch_bounds__(512) void window_embed_kernel(
    const f4* __restrict__ x, f4* __restrict__ out) {
  const int tid   = threadIdx.x;
  const int lane  = tid & 127;     // f4 index within a D-row
  const int group = tid >> 7;      // which 16-row sub-chunk

  const int tbase = blockIdx.x * R + group * GR;     // first t of my chunk
  const long long row0 = (long long)blockIdx.y * T_DIM + tbase;

  const f4* __restrict__ xb = x + row0 * D4 + lane;
  f4* __restrict__ ob = out + row0 * (long long)ROW_OUT + lane;

  const f4 zero = (f4)0.f;

  // Prime the 5-row rolling window: win[q] holds x row (tbase+q) at my lane.
  f4 win[W];
#pragma unroll
  for (int q = 0; q < W; ++q)
    win[q] = (tbase + q < T_DIM) ? __builtin_nontemporal_load(&xb[q * D4])
                                 : zero;

  // Invariant before iter i: win[(i+w)%5] == x row (tbase+i+w), w=0..4.
#pragma unroll
  for (int i = 0; i < GR; ++i) {
#pragma unroll
    for (int w = 0; w < W; ++w) {
      __builtin_nontemporal_store(win[(i + w) % W],
                                  &ob[(long long)i * ROW_OUT + w * D4]);
    }
    // Refill slot i%5 with row tbase+i+5 (consumed 5 iterations later).
    win[i % W] = (tbase + i + W < T_DIM)
                     ? __builtin_nontemporal_load(&xb[(i + W) * D4])
                     : zero;
  }
}

extern "C" void kernel_launch(void* const* d_in, const int* in_sizes, int n_in,
                              void* d_out, int out_size, void* d_ws, size_t ws_size,
                              hipStream_t stream) {
  const f4* x = (const f4*)d_in[0];
  f4* out = (f4*)d_out;

  dim3 grid(T_DIM / R, 16);   // (32, 16) = 512 blocks
  window_embed_kernel<<<grid, 512, 0, stream>>>(x, out);
}

// Round 8
// 69.939 us; speedup vs baseline: 1.2362x; 1.2239x over previous
//
#include <hip/hip_runtime.h>

// WindowEmbedding: x[B,T,D] fp32 -> out[B,T,D*W], slot w = x shifted left by w,
// zero past sequence end. B=16, T=2048, D=512, W=5.
//
// Identity: out[(b*T+t)*640 + j] = x[((b*T+t)*128) + j] for j in [0,640),
// valid while t + j/128 < T, else 0 -> each output row is a contiguous
// 640-float4 slice of x. Pure overlapping copy: each block owns R=32 rows,
// reads via the NORMAL cached path (intra-block/neighbor-halo reuse hits
// L1/L2 — nt loads regressed +21%, R7), nontemporal-stores the contiguous
// output (nt-only; plain stores write-allocate-thrash +23%, R5; sc0/sc1
// full bypass is incorrect under the harness's cached memset, R6).
//
// Best measured configuration: 70.2 us ~= 5.85 TB/s effective on ~411 MB,
// within ~4-7% of the 6.29 TB/s copy ceiling on this mixed 82%-write stream.

typedef float f4 __attribute__((ext_vector_type(4)));

constexpr int T_DIM = 2048;
constexpr int D4 = 128;            // 512 floats / 4 per float4
constexpr int W = 5;
constexpr int R = 32;              // output rows per block
constexpr int ROW_OUT = W * D4;    // 640 f4 per output row

__global__ __launch_bounds__(256) void window_embed_kernel(
    const f4* __restrict__ x, f4* __restrict__ out) {
  const int tid  = threadIdx.x;
  const int lane = tid & 127;      // f4 index within a D-row
  const int half = tid >> 7;       // two 128-thread groups, 16 rows each

  const int t0 = blockIdx.x * R;
  const long long row0 = (long long)blockIdx.y * T_DIM + t0;

  const f4* __restrict__ xb = x + row0 * D4 + lane;
  f4* __restrict__ ob = out + row0 * (long long)ROW_OUT + lane;

  const f4 zero = (f4)0.f;

#pragma unroll 4
  for (int i = 0; i < R / 2; ++i) {
    const int r = half * (R / 2) + i;      // row within the block's chunk
    f4 v[W];
#pragma unroll
    for (int q = 0; q < W; ++q) {
      // source row t0 + r + q; guard past end of sequence
      v[q] = (t0 + r + q < T_DIM) ? xb[(r + q) * D4] : zero;
    }
#pragma unroll
    for (int q = 0; q < W; ++q) {
      __builtin_nontemporal_store(v[q], &ob[(long long)r * ROW_OUT + q * D4]);
    }
  }
}

extern "C" void kernel_launch(void* const* d_in, const int* in_sizes, int n_in,
                              void* d_out, int out_size, void* d_ws, size_t ws_size,
                              hipStream_t stream) {
  const f4* x = (const f4*)d_in[0];
  f4* out = (f4*)d_out;

  dim3 grid(T_DIM / R, 16);   // (64, 16) = 1024 blocks
  window_embed_kernel<<<grid, 256, 0, stream>>>(x, out);
}